// Round 2
// baseline (808.702 us; speedup 1.0000x reference)
//
#include <hip/hip_runtime.h>
#include <hip/hip_bf16.h>

#define BATCH 8192
#define DIM   2048

typedef __attribute__((ext_vector_type(8))) short  bf16x8;
typedef __attribute__((ext_vector_type(4))) float  f32x4;

__device__ __forceinline__ unsigned short f2bf(float f) {
    __hip_bfloat16 h = __float2bfloat16(f);
    return *reinterpret_cast<unsigned short*>(&h);
}

// jax.nn.gelu default approximate=True (tanh form)
__device__ __forceinline__ float gelu_f(float x) {
    const float c0 = 0.7978845608028654f;
    float x3 = x * x * x;
    float t  = tanhf(c0 * (x + 0.044715f * x3));
    return 0.5f * x * (1.0f + t);
}

__device__ __forceinline__ void gload_lds16(const void* g, void* lds) {
    __builtin_amdgcn_global_load_lds(
        (const __attribute__((address_space(1))) unsigned int*)g,
        (__attribute__((address_space(3))) unsigned int*)lds,
        16, 0, 0);
}

// ---------------- routing ----------------
__global__ void minmax_k(const float* __restrict__ u, float* __restrict__ mm, int n) {
    __shared__ float smn[1024], smx[1024];
    int t = threadIdx.x;
    const float4* p = reinterpret_cast<const float4*>(u);
    float4 a = p[2 * t], b = p[2 * t + 1];
    float mn = fminf(fminf(fminf(a.x, a.y), fminf(a.z, a.w)),
                     fminf(fminf(b.x, b.y), fminf(b.z, b.w)));
    float mx = fmaxf(fmaxf(fmaxf(a.x, a.y), fmaxf(a.z, a.w)),
                     fmaxf(fmaxf(b.x, b.y), fmaxf(b.z, b.w)));
    smn[t] = mn; smx[t] = mx;
    __syncthreads();
    for (int s = 512; s > 0; s >>= 1) {
        if (t < s) {
            smn[t] = fminf(smn[t], smn[t + s]);
            smx[t] = fmaxf(smx[t], smx[t + s]);
        }
        __syncthreads();
    }
    if (t == 0) { mm[0] = smn[0]; mm[1] = smx[0]; }
}

__global__ void route_k(const float* __restrict__ unc, const float* __restrict__ mm,
                        const float* __restrict__ rw1, const float* __restrict__ rb1,
                        const float* __restrict__ rw2, const float* __restrict__ rb2,
                        const float* __restrict__ rw3, const float* __restrict__ rb3,
                        int* __restrict__ routing, float* __restrict__ mask_out, int n) {
    int i = blockIdx.x * 256 + threadIdx.x;
    if (i >= n) return;
    float u = (unc[i] - mm[0]) / (mm[1] - mm[0] + 1e-8f);
    float h1[32];
#pragma unroll
    for (int j = 0; j < 32; ++j) h1[j] = fmaxf(u * rw1[j] + rb1[j], 0.0f);
    float h2[16];
#pragma unroll
    for (int j = 0; j < 16; ++j) {
        float s = rb2[j];
#pragma unroll
        for (int k = 0; k < 32; ++k) s += h1[k] * rw2[k * 16 + j];
        h2[j] = fmaxf(s, 0.0f);
    }
    float lg[3];
#pragma unroll
    for (int j = 0; j < 3; ++j) {
        float s = rb3[j];
#pragma unroll
        for (int k = 0; k < 16; ++k) s += h2[k] * rw3[k * 3 + j];
        lg[j] = s;
    }
    int idx = 0; float best = lg[0];
    if (lg[1] > best) { best = lg[1]; idx = 1; }
    if (lg[2] > best) { best = lg[2]; idx = 2; }
    routing[i] = idx;
    mask_out[i] = (float)idx;
}

// ---------------- conversions ----------------
__global__ void convx_k(const float* __restrict__ in, unsigned short* __restrict__ out, int n8) {
    int i = blockIdx.x * 256 + threadIdx.x;
    if (i >= n8) return;
    const float4* p = reinterpret_cast<const float4*>(in) + (size_t)2 * i;
    float4 a = p[0], b = p[1];
    bf16x8 o;
    o[0] = (short)f2bf(a.x); o[1] = (short)f2bf(a.y);
    o[2] = (short)f2bf(a.z); o[3] = (short)f2bf(a.w);
    o[4] = (short)f2bf(b.x); o[5] = (short)f2bf(b.y);
    o[6] = (short)f2bf(b.z); o[7] = (short)f2bf(b.w);
    *(reinterpret_cast<bf16x8*>(out) + i) = o;
}

// W [K][N] f32 -> Wt [N][K] bf16 (transposed), LDS-tiled
__global__ void convw_k(const float* __restrict__ W, unsigned short* __restrict__ Wt) {
    __shared__ float t[32][33];
    int n0 = blockIdx.x * 32, k0 = blockIdx.y * 32;
    int tx = threadIdx.x, ty = threadIdx.y;   // 32 x 8
#pragma unroll
    for (int r = 0; r < 4; ++r)
        t[ty + 8 * r][tx] = W[(size_t)(k0 + ty + 8 * r) * DIM + n0 + tx];
    __syncthreads();
#pragma unroll
    for (int r = 0; r < 4; ++r)
        Wt[(size_t)(n0 + ty + 8 * r) * DIM + k0 + tx] = f2bf(t[tx][ty + 8 * r]);
}

// ---------------- GEMM + GELU + routed write ----------------
// C[m][n] = gelu(sum_k A[m][k] * Bt[n][k] + bias[n])
__launch_bounds__(256)
__global__ void gemm_k(const unsigned short* __restrict__ A,
                       const unsigned short* __restrict__ Bt,
                       unsigned short* __restrict__ Ob,   // [M][N] bf16 scratch out
                       const float* __restrict__ bias,    // [N]
                       const int* __restrict__ routing,
                       float* __restrict__ Of,            // [M][N] f32 final out
                       int match, int store_ob) {
    constexpr int N = DIM, K = DIM;
    __shared__ short smem[8192];          // 16 KB: lsA | lsB, reused as lsC in epilogue
    short* lsA = smem;
    short* lsB = smem + 4096;

    const int tid  = threadIdx.x;
    // XCD-bijective swizzle: 1024 wgs, 8 XCDs -> each XCD owns 128 contiguous tiles
    const int wg   = (blockIdx.x & 7) * 128 + (blockIdx.x >> 3);
    const int bm   = wg >> 4;             // 64 M-tiles
    const int bn   = wg & 15;             // 16 N-tiles
    const int m0   = bm * 128, n0 = bn * 128;
    const int wave = tid >> 6, lane = tid & 63;
    const int wr   = wave >> 1, wc = wave & 1;

    const int rS = tid >> 2;
    const int cS = (tid & 3) * 8;
    const char* gA = (const char*)(A  + (size_t)(m0 + rS) * K + cS);
    const char* gB = (const char*)(Bt + (size_t)(n0 + rS) * K + cS);
    char* lA = (char*)lsA + wave * 1024;
    char* lB = (char*)lsB + wave * 1024;

    f32x4 acc[4][4];
#pragma unroll
    for (int i = 0; i < 4; ++i)
#pragma unroll
        for (int j = 0; j < 4; ++j)
            acc[i][j] = (f32x4){0.f, 0.f, 0.f, 0.f};

    const int lrow = lane & 15;
    const int kb   = (lane >> 4) * 8;
    const short* pA = lsA + (wr * 64 + lrow) * 32 + kb;
    const short* pB = lsB + (wc * 64 + lrow) * 32 + kb;

    for (int kt = 0; kt < K / 32; ++kt) {
        const char* ga = gA + kt * 64;
        const char* gb = gB + kt * 64;
        gload_lds16(ga,                      lA);
        gload_lds16(ga + (size_t)64 * K * 2, lA + 4096);
        gload_lds16(gb,                      lB);
        gload_lds16(gb + (size_t)64 * K * 2, lB + 4096);
        __syncthreads();

        bf16x8 af[4], bfr[4];
#pragma unroll
        for (int i = 0; i < 4; ++i) af[i]  = *(const bf16x8*)(pA + i * 16 * 32);
#pragma unroll
        for (int j = 0; j < 4; ++j) bfr[j] = *(const bf16x8*)(pB + j * 16 * 32);
#pragma unroll
        for (int i = 0; i < 4; ++i)
#pragma unroll
            for (int j = 0; j < 4; ++j)
                acc[i][j] = __builtin_amdgcn_mfma_f32_16x16x32_bf16(af[i], bfr[j], acc[i][j], 0, 0, 0);
        __syncthreads();
    }

    // ---- epilogue: C col = lane&15, row = (lane>>4)*4 + r ----
    const int crow0 = (lane >> 4) * 4;
    float bcol[4];
#pragma unroll
    for (int jb = 0; jb < 4; ++jb) bcol[jb] = bias[n0 + wc * 64 + jb * 16 + lrow];

    constexpr int CPAD = 132;             // padded LDS row stride (shorts)
    short* lsC = smem;                    // 32*132*2B = 8448 B, K-loop done

#pragma unroll
    for (int i = 0; i < 4; ++i) {
        float v[4][4];
#pragma unroll
        for (int jb = 0; jb < 4; ++jb)
#pragma unroll
            for (int r = 0; r < 4; ++r)
                v[jb][r] = gelu_f(acc[i][jb][r] + bcol[jb]);

        // routed f32 write: 16 lanes x 4B = 64B contiguous segments, no RMW
#pragma unroll
        for (int r = 0; r < 4; ++r) {
            int row = m0 + wr * 64 + i * 16 + crow0 + r;
            if (routing[row] == match) {
                size_t base = (size_t)row * N + n0 + wc * 64 + lrow;
#pragma unroll
                for (int jb = 0; jb < 4; ++jb) Of[base + jb * 16] = v[jb][r];
            }
        }

        if (store_ob) {
            // stage bf16 tile in LDS, rows rl = wr*16 + crow0 + r
#pragma unroll
            for (int r = 0; r < 4; ++r)
#pragma unroll
                for (int jb = 0; jb < 4; ++jb)
                    lsC[(wr * 16 + crow0 + r) * CPAD + wc * 64 + jb * 16 + lrow] = f2bf(v[jb][r]);
        }
        __syncthreads();
        if (store_ob) {
            // coalesced copy-out: 16 lanes x 16B = 256B per row
#pragma unroll
            for (int p = 0; p < 2; ++p) {
                int t  = p * 256 + tid;
                int rl = t >> 4;             // 0..31
                int c8 = (t & 15) * 8;       // col in shorts
                int grow = m0 + (rl >> 4) * 64 + i * 16 + (rl & 15);
                *(bf16x8*)(Ob + (size_t)grow * N + n0 + c8) =
                    *(const bf16x8*)(lsC + rl * CPAD + c8);
            }
        }
        __syncthreads();
    }
}

extern "C" void kernel_launch(void* const* d_in, const int* in_sizes, int n_in,
                              void* d_out, int out_size, void* d_ws, size_t ws_size,
                              hipStream_t stream) {
    const float* x   = (const float*)d_in[0];
    const float* unc = (const float*)d_in[1];
    const float* Ws  = (const float*)d_in[2];
    const float* bs  = (const float*)d_in[3];
    const float* rw1 = (const float*)d_in[4];
    const float* rb1 = (const float*)d_in[5];
    const float* rw2 = (const float*)d_in[6];
    const float* rb2 = (const float*)d_in[7];
    const float* rw3 = (const float*)d_in[8];
    const float* rb3 = (const float*)d_in[9];
    float* out  = (float*)d_out;
    float* mask = out + (size_t)BATCH * DIM;

    // ws layout: Wb (8MB) | hb0 (32MB) | hb1 (32MB) | routing (32KB) | mm (8B)
    char* ws = (char*)d_ws;
    unsigned short* Wb  = (unsigned short*)ws;
    unsigned short* hb0 = (unsigned short*)(ws + (size_t)8  * 1024 * 1024);
    unsigned short* hb1 = (unsigned short*)(ws + (size_t)40 * 1024 * 1024);
    int*   routing = (int*)  (ws + (size_t)72 * 1024 * 1024);
    float* mm      = (float*)(ws + (size_t)72 * 1024 * 1024 + 64 * 1024);

    minmax_k<<<1, 1024, 0, stream>>>(unc, mm, BATCH);
    route_k<<<BATCH / 256, 256, 0, stream>>>(unc, mm, rw1, rb1, rw2, rb2, rw3, rb3,
                                             routing, mask, BATCH);
    convx_k<<<(BATCH * DIM / 8 + 255) / 256, 256, 0, stream>>>(x, hb0, BATCH * DIM / 8);

    // chain: hb0(x) -W0-> hb1(lvl0) -W1-> hb0(lvl1) -W2-> hb1 -W3-> (lvl2, no Ob)
    const unsigned short* ins[4]  = {hb0, hb1, hb0, hb1};
    unsigned short*       outs[4] = {hb1, hb0, hb1, hb0};
    const int matches[4]  = {0, 1, -1, 2};
    const int store_ob[4] = {1, 1, 1, 0};
    for (int l = 0; l < 4; ++l) {
        convw_k<<<dim3(64, 64), dim3(32, 8), 0, stream>>>(Ws + (size_t)l * DIM * DIM, Wb);
        gemm_k<<<1024, 256, 0, stream>>>(ins[l], Wb, outs[l], bs + (size_t)l * DIM,
                                         routing, out, matches[l], store_ob[l]);
    }
}

// Round 3
// 640.320 us; speedup vs baseline: 1.2630x; 1.2630x over previous
//
#include <hip/hip_runtime.h>
#include <hip/hip_bf16.h>

#define BATCH 8192
#define DIM   2048

typedef __attribute__((ext_vector_type(8))) short  bf16x8;
typedef __attribute__((ext_vector_type(4))) float  f32x4;

__device__ __forceinline__ unsigned short f2bf(float f) {
    __hip_bfloat16 h = __float2bfloat16(f);
    return *reinterpret_cast<unsigned short*>(&h);
}

// jax.nn.gelu default approximate=True (tanh form)
__device__ __forceinline__ float gelu_f(float x) {
    const float c0 = 0.7978845608028654f;
    float x3 = x * x * x;
    float t  = tanhf(c0 * (x + 0.044715f * x3));
    return 0.5f * x * (1.0f + t);
}

__device__ __forceinline__ void gload_lds16(const void* g, void* lds) {
    __builtin_amdgcn_global_load_lds(
        (const __attribute__((address_space(1))) unsigned int*)g,
        (__attribute__((address_space(3))) unsigned int*)lds,
        16, 0, 0);
}

// ---------------- routing ----------------
__global__ void minmax_k(const float* __restrict__ u, float* __restrict__ mm, int n) {
    __shared__ float smn[1024], smx[1024];
    int t = threadIdx.x;
    const float4* p = reinterpret_cast<const float4*>(u);
    float4 a = p[2 * t], b = p[2 * t + 1];
    float mn = fminf(fminf(fminf(a.x, a.y), fminf(a.z, a.w)),
                     fminf(fminf(b.x, b.y), fminf(b.z, b.w)));
    float mx = fmaxf(fmaxf(fmaxf(a.x, a.y), fmaxf(a.z, a.w)),
                     fmaxf(fmaxf(b.x, b.y), fmaxf(b.z, b.w)));
    smn[t] = mn; smx[t] = mx;
    __syncthreads();
    for (int s = 512; s > 0; s >>= 1) {
        if (t < s) {
            smn[t] = fminf(smn[t], smn[t + s]);
            smx[t] = fmaxf(smx[t], smx[t + s]);
        }
        __syncthreads();
    }
    if (t == 0) { mm[0] = smn[0]; mm[1] = smx[0]; }
}

// Weights staged in LDS: kills the serial uniform-s_load chain that made this
// kernel take 165us (VALUBusy ~1%, pure scalar-load latency).
__global__ void route_k(const float* __restrict__ unc, const float* __restrict__ mm,
                        const float* __restrict__ rw1, const float* __restrict__ rb1,
                        const float* __restrict__ rw2, const float* __restrict__ rb2,
                        const float* __restrict__ rw3, const float* __restrict__ rb3,
                        int* __restrict__ routing, float* __restrict__ mask_out, int n) {
    __shared__ float s_w1[32], s_b1[32], s_w2[512], s_b2[16], s_w3[48], s_b3[3];
    const int t = threadIdx.x;
    if (t < 32) { s_w1[t] = rw1[t]; s_b1[t] = rb1[t]; }
#pragma unroll
    for (int i2 = 0; i2 < 2; ++i2) s_w2[i2 * 256 + t] = rw2[i2 * 256 + t];
    if (t < 16) s_b2[t] = rb2[t];
    if (t < 48) s_w3[t] = rw3[t];
    if (t < 3)  s_b3[t] = rb3[t];
    __syncthreads();

    int i = blockIdx.x * 256 + t;
    if (i >= n) return;
    float u = (unc[i] - mm[0]) / (mm[1] - mm[0] + 1e-8f);
    float h1[32];
#pragma unroll
    for (int j = 0; j < 32; ++j) h1[j] = fmaxf(u * s_w1[j] + s_b1[j], 0.0f);
    float h2[16];
#pragma unroll
    for (int j = 0; j < 16; ++j) {
        float s = s_b2[j];
#pragma unroll
        for (int k = 0; k < 32; ++k) s += h1[k] * s_w2[k * 16 + j];
        h2[j] = fmaxf(s, 0.0f);
    }
    float lg[3];
#pragma unroll
    for (int j = 0; j < 3; ++j) {
        float s = s_b3[j];
#pragma unroll
        for (int k = 0; k < 16; ++k) s += h2[k] * s_w3[k * 3 + j];
        lg[j] = s;
    }
    // argmax(softmax) == argmax(logits); strict '>' = first-index ties (jnp.argmax)
    int idx = 0; float best = lg[0];
    if (lg[1] > best) { best = lg[1]; idx = 1; }
    if (lg[2] > best) { best = lg[2]; idx = 2; }
    routing[i] = idx;
    mask_out[i] = (float)idx;
}

// ---------------- conversions ----------------
__global__ void convx_k(const float* __restrict__ in, unsigned short* __restrict__ out, int n8) {
    int i = blockIdx.x * 256 + threadIdx.x;
    if (i >= n8) return;
    const float4* p = reinterpret_cast<const float4*>(in) + (size_t)2 * i;
    float4 a = p[0], b = p[1];
    bf16x8 o;
    o[0] = (short)f2bf(a.x); o[1] = (short)f2bf(a.y);
    o[2] = (short)f2bf(a.z); o[3] = (short)f2bf(a.w);
    o[4] = (short)f2bf(b.x); o[5] = (short)f2bf(b.y);
    o[6] = (short)f2bf(b.z); o[7] = (short)f2bf(b.w);
    *(reinterpret_cast<bf16x8*>(out) + i) = o;
}

// W [K][N] f32 -> Wt [N][K] bf16 (transposed), LDS-tiled
__global__ void convw_k(const float* __restrict__ W, unsigned short* __restrict__ Wt) {
    __shared__ float t[32][33];
    int n0 = blockIdx.x * 32, k0 = blockIdx.y * 32;
    int tx = threadIdx.x, ty = threadIdx.y;   // 32 x 8
#pragma unroll
    for (int r = 0; r < 4; ++r)
        t[ty + 8 * r][tx] = W[(size_t)(k0 + ty + 8 * r) * DIM + n0 + tx];
    __syncthreads();
#pragma unroll
    for (int r = 0; r < 4; ++r)
        Wt[(size_t)(n0 + ty + 8 * r) * DIM + k0 + tx] = f2bf(t[tx][ty + 8 * r]);
}

// ---------------- GEMM + GELU + routed write ----------------
// C[m][n] = gelu(sum_k A[m][k] * Bt[n][k] + bias[n])
// Both outputs (bf16 Ob, routed f32 Of) staged through LDS so every global
// store is a full 256-512B contiguous segment (no partial-cacheline RMW).
__launch_bounds__(256)
__global__ void gemm_k(const unsigned short* __restrict__ A,
                       const unsigned short* __restrict__ Bt,
                       unsigned short* __restrict__ Ob,   // [M][N] bf16 scratch out
                       const float* __restrict__ bias,    // [N]
                       const int* __restrict__ routing,
                       float* __restrict__ Of,            // [M][N] f32 final out
                       int match, int store_ob) {
    constexpr int N = DIM, K = DIM;
    // 25.6 KB: K-loop uses [0,16KB) as lsA|lsB; epilogue uses lsC (8.4KB) + lsF (16.9KB)
    __shared__ short smem[12800];
    short* lsA = smem;
    short* lsB = smem + 4096;

    const int tid  = threadIdx.x;
    const int wg   = blockIdx.x;          // no swizzle: working set is L3-resident
    const int bm   = wg >> 4;             // 64 M-tiles
    const int bn   = wg & 15;             // 16 N-tiles
    const int m0   = bm * 128, n0 = bn * 128;
    const int wave = tid >> 6, lane = tid & 63;
    const int wr   = wave >> 1, wc = wave & 1;

    const int rS = tid >> 2;
    const int cS = (tid & 3) * 8;
    const char* gA = (const char*)(A  + (size_t)(m0 + rS) * K + cS);
    const char* gB = (const char*)(Bt + (size_t)(n0 + rS) * K + cS);
    char* lA = (char*)lsA + wave * 1024;
    char* lB = (char*)lsB + wave * 1024;

    f32x4 acc[4][4];
#pragma unroll
    for (int i = 0; i < 4; ++i)
#pragma unroll
        for (int j = 0; j < 4; ++j)
            acc[i][j] = (f32x4){0.f, 0.f, 0.f, 0.f};

    const int lrow = lane & 15;
    const int kb   = (lane >> 4) * 8;
    const short* pA = lsA + (wr * 64 + lrow) * 32 + kb;
    const short* pB = lsB + (wc * 64 + lrow) * 32 + kb;

    for (int kt = 0; kt < K / 32; ++kt) {
        const char* ga = gA + kt * 64;
        const char* gb = gB + kt * 64;
        gload_lds16(ga,                      lA);
        gload_lds16(ga + (size_t)64 * K * 2, lA + 4096);
        gload_lds16(gb,                      lB);
        gload_lds16(gb + (size_t)64 * K * 2, lB + 4096);
        __syncthreads();

        bf16x8 af[4], bfr[4];
#pragma unroll
        for (int i = 0; i < 4; ++i) af[i]  = *(const bf16x8*)(pA + i * 16 * 32);
#pragma unroll
        for (int j = 0; j < 4; ++j) bfr[j] = *(const bf16x8*)(pB + j * 16 * 32);
#pragma unroll
        for (int i = 0; i < 4; ++i)
#pragma unroll
            for (int j = 0; j < 4; ++j)
                acc[i][j] = __builtin_amdgcn_mfma_f32_16x16x32_bf16(af[i], bfr[j], acc[i][j], 0, 0, 0);
        __syncthreads();
    }

    // ---- epilogue: C col = lane&15, row = (lane>>4)*4 + r ----
    const int crow0 = (lane >> 4) * 4;
    float bcol[4];
#pragma unroll
    for (int jb = 0; jb < 4; ++jb) bcol[jb] = bias[n0 + wc * 64 + jb * 16 + lrow];

    constexpr int CPAD = 132;
    short* lsC = smem;                         // [32][132] shorts = 8448 B
    float* lsF = (float*)(smem + 4224);        // [32][132] floats = 16896 B @ byte 8448

#pragma unroll
    for (int i = 0; i < 4; ++i) {
        float v[4][4];
#pragma unroll
        for (int jb = 0; jb < 4; ++jb)
#pragma unroll
            for (int r = 0; r < 4; ++r)
                v[jb][r] = gelu_f(acc[i][jb][r] + bcol[jb]);

        // stage the 32x128 chunk in LDS (both precisions)
#pragma unroll
        for (int r = 0; r < 4; ++r) {
            int rl = wr * 16 + crow0 + r;
#pragma unroll
            for (int jb = 0; jb < 4; ++jb) {
                int cc = wc * 64 + jb * 16 + lrow;
                lsF[rl * CPAD + cc] = v[jb][r];
                if (store_ob) lsC[rl * CPAD + cc] = f2bf(v[jb][r]);
            }
        }
        __syncthreads();

        if (store_ob) {
            // bf16 copy-out: 16 lanes x 16B = 256B contiguous per row
#pragma unroll
            for (int p = 0; p < 2; ++p) {
                int t  = p * 256 + tid;
                int rl = t >> 4;             // 0..31
                int c8 = (t & 15) * 8;       // col in shorts
                int grow = m0 + (rl >> 4) * 64 + i * 16 + (rl & 15);
                *(bf16x8*)(Ob + (size_t)grow * N + n0 + c8) =
                    *(const bf16x8*)(lsC + rl * CPAD + c8);
            }
        }
        // routed f32 copy-out: 32 lanes x 16B = 512B contiguous per row
#pragma unroll
        for (int p = 0; p < 4; ++p) {
            int t2 = p * 256 + tid;          // 0..1023
            int rl = t2 >> 5;                // 0..31
            int c4 = (t2 & 31) * 4;          // float col
            int grow = m0 + (rl >> 4) * 64 + i * 16 + (rl & 15);
            if (routing[grow] == match)
                *(float4*)(Of + (size_t)grow * N + n0 + c4) =
                    *(const float4*)(lsF + rl * CPAD + c4);
        }
        __syncthreads();
    }
}

extern "C" void kernel_launch(void* const* d_in, const int* in_sizes, int n_in,
                              void* d_out, int out_size, void* d_ws, size_t ws_size,
                              hipStream_t stream) {
    const float* x   = (const float*)d_in[0];
    const float* unc = (const float*)d_in[1];
    const float* Ws  = (const float*)d_in[2];
    const float* bs  = (const float*)d_in[3];
    const float* rw1 = (const float*)d_in[4];
    const float* rb1 = (const float*)d_in[5];
    const float* rw2 = (const float*)d_in[6];
    const float* rb2 = (const float*)d_in[7];
    const float* rw3 = (const float*)d_in[8];
    const float* rb3 = (const float*)d_in[9];
    float* out  = (float*)d_out;
    float* mask = out + (size_t)BATCH * DIM;

    // ws layout: Wb (8MB) | hb0 (32MB) | hb1 (32MB) | routing (32KB) | mm (8B)
    char* ws = (char*)d_ws;
    unsigned short* Wb  = (unsigned short*)ws;
    unsigned short* hb0 = (unsigned short*)(ws + (size_t)8  * 1024 * 1024);
    unsigned short* hb1 = (unsigned short*)(ws + (size_t)40 * 1024 * 1024);
    int*   routing = (int*)  (ws + (size_t)72 * 1024 * 1024);
    float* mm      = (float*)(ws + (size_t)72 * 1024 * 1024 + 64 * 1024);

    minmax_k<<<1, 1024, 0, stream>>>(unc, mm, BATCH);
    route_k<<<BATCH / 256, 256, 0, stream>>>(unc, mm, rw1, rb1, rw2, rb2, rw3, rb3,
                                             routing, mask, BATCH);
    convx_k<<<(BATCH * DIM / 8 + 255) / 256, 256, 0, stream>>>(x, hb0, BATCH * DIM / 8);

    // chain: hb0(x) -W0-> hb1(lvl0) -W1-> hb0(lvl1) -W2-> hb1 -W3-> (lvl2, no Ob)
    const unsigned short* ins[4]  = {hb0, hb1, hb0, hb1};
    unsigned short*       outs[4] = {hb1, hb0, hb1, hb0};
    const int matches[4]  = {0, 1, -1, 2};
    const int store_ob[4] = {1, 1, 1, 0};
    for (int l = 0; l < 4; ++l) {
        convw_k<<<dim3(64, 64), dim3(32, 8), 0, stream>>>(Ws + (size_t)l * DIM * DIM, Wb);
        gemm_k<<<1024, 256, 0, stream>>>(ins[l], Wb, outs[l], bs + (size_t)l * DIM,
                                         routing, out, matches[l], store_ob[l]);
    }
}